// Round 12
// baseline (76.490 us; speedup 1.0000x reference)
//
#include <hip/hip_runtime.h>
#include <hip/hip_bf16.h>

#define BCH 32   // B*C heads
#define NN  2048
#define DD  64   // F = H = O

typedef __attribute__((ext_vector_type(8)))  __bf16 bf16x8;
typedef __attribute__((ext_vector_type(4)))  __bf16 bf16x4;
typedef __attribute__((ext_vector_type(4)))  float  f32x4;
typedef __attribute__((ext_vector_type(16))) float  f32x16;
typedef __attribute__((ext_vector_type(2)))  int    i32x2;
typedef __attribute__((ext_vector_type(4)))  int    i32x4;
typedef __attribute__((ext_vector_type(2)))  unsigned int u32x2;

__device__ inline f32x4 mfma16(bf16x8 a, bf16x8 b, f32x4 c) {
    return __builtin_amdgcn_mfma_f32_16x16x32_bf16(a, b, c, 0, 0, 0);
}
__device__ inline f32x16 mfma32(bf16x8 a, bf16x8 b, f32x16 c) {
    return __builtin_amdgcn_mfma_f32_32x32x16_bf16(a, b, c, 0, 0, 0);
}
__device__ inline void gload16(const void* g, void* l) {
    __builtin_amdgcn_global_load_lds(
        (const __attribute__((address_space(1))) void*)g,
        (__attribute__((address_space(3))) void*)l, 16, 0, 0);
}
// permlane32_swap BUILTIN (validated round 9)
__device__ inline void plswap(int& a, int& b) {
    u32x2 r = __builtin_amdgcn_permlane32_swap((unsigned)a, (unsigned)b, false, false);
    a = (int)r[0];
    b = (int)r[1];
}

// ---------------------------------------------------------------------------
// Kernel 1 v2: redundancy moved from x (HBM) to weights (L2-hot).
// grid 1024 (32 bc x 32 strips of 64 n), block 256 = 4 waves.
// Wave w owns x-rows w*16..+16 (loaded ONCE); loops hb over all 4 h-blocks.
// Same validated mappings as rounds 6-11 with w <-> hb roles swapped.
// ---------------------------------------------------------------------------
__global__ __launch_bounds__(256) void prep_kernel(
    const float* __restrict__ x,
    const float* __restrict__ W1, const float* __restrict__ b1,
    const float* __restrict__ W2, const float* __restrict__ b2,
    const float* __restrict__ W3,
    __bf16* __restrict__ e1, __bf16* __restrict__ e2, __bf16* __restrict__ vT)
{
    const int t   = threadIdx.x;
    const int blk = blockIdx.x;
    const int bc  = blk >> 5, st = blk & 31;
    const long grow = (long)bc * NN + st * 64;
    const int w = t >> 6, l = t & 63, lg = l >> 4, li = l & 15;

    // this wave's 16 x-rows, loaded once
    bf16x8 a[2];
    #pragma unroll
    for (int kk = 0; kk < 2; ++kk) {
        const float* p = x + (grow + w * 16 + li) * DD + kk * 32 + lg * 8;
        f32x4 v0 = *(const f32x4*)p, v1 = *(const f32x4*)(p + 4);
        #pragma unroll
        for (int j = 0; j < 4; ++j) { a[kk][j] = (__bf16)v0[j]; a[kk][4 + j] = (__bf16)v1[j]; }
    }

    #pragma unroll
    for (int hb = 0; hb < 4; ++hb) {
        bf16x8 wf1[2], wf2[2], wf3[2];
        #pragma unroll
        for (int kk = 0; kk < 2; ++kk) {
            const float* p1 = W1 + (hb * 16 + li) * DD + kk * 32 + lg * 8;
            const float* p2 = W2 + (hb * 16 + li) * DD + kk * 32 + lg * 8;
            const float* p3 = W3 + (hb * 16 + li) * DD + kk * 32 + lg * 8;
            f32x4 u0 = *(const f32x4*)p1, u1 = *(const f32x4*)(p1 + 4);
            f32x4 v0 = *(const f32x4*)p2, v1 = *(const f32x4*)(p2 + 4);
            f32x4 t0 = *(const f32x4*)p3, t1 = *(const f32x4*)(p3 + 4);
            #pragma unroll
            for (int j = 0; j < 4; ++j) {
                wf1[kk][j] = (__bf16)u0[j]; wf1[kk][4 + j] = (__bf16)u1[j];
                wf2[kk][j] = (__bf16)v0[j]; wf2[kk][4 + j] = (__bf16)v1[j];
                wf3[kk][j] = (__bf16)t0[j]; wf3[kk][4 + j] = (__bf16)t1[j];
            }
        }
        const f32x4 bq1 = *(const f32x4*)(b1 + hb * 16 + lg * 4);
        const f32x4 bq2 = *(const f32x4*)(b2 + hb * 16 + lg * 4);

        f32x4 acc1 = {0.f,0.f,0.f,0.f}, acc2 = {0.f,0.f,0.f,0.f}, acc3 = {0.f,0.f,0.f,0.f};
        #pragma unroll
        for (int kk = 0; kk < 2; ++kk) {
            acc1 = mfma16(wf1[kk], a[kk], acc1);   // D[h][n]
            acc2 = mfma16(wf2[kk], a[kk], acc2);   // D[h][n]
            acc3 = mfma16(a[kk], wf3[kk], acc3);   // D[n][o]
        }
        bf16x4 q1, q2, q3;
        #pragma unroll
        for (int r = 0; r < 4; ++r) {
            q1[r] = (__bf16)(acc1[r] + bq1[r]);
            q2[r] = (__bf16)(acc2[r] + bq2[r]);
            q3[r] = (__bf16)acc3[r];
        }
        // n = grow + w*16 + li ; h = hb*16 + lg*4 + r
        *(bf16x4*)&e1[(grow + w * 16 + li) * DD + hb * 16 + lg * 4] = q1;
        *(bf16x4*)&e2[(grow + w * 16 + li) * DD + hb * 16 + lg * 4] = q2;
        // o = hb*16 + li ; n = st*64 + w*16 + lg*4 + r
        *(bf16x4*)&vT[((long)bc * DD + hb * 16 + li) * NN + st * 64 + w * 16 + lg * 4] = q3;
    }
}

// ---------------------------------------------------------------------------
// Kernel 2 v3: software-pipelined S/PV. grid 1024 (XCD-grouped), block 256 =
// 4 waves (2 wn x 2 wm), 4 blocks/CU. Per iteration: stage(kt+2) ->
// vmcnt(4)+barrier -> S(kt+1)+vf(kt+1)->regs  ||  PV(kt) from regs -> pack
// Q(kt+1) -> barrier. Q and vf double-buffered in registers (static names).
// ---------------------------------------------------------------------------
__global__ __launch_bounds__(256, 4) void fused_kernel(
    const __bf16* __restrict__ e1, const __bf16* __restrict__ e2,
    const __bf16* __restrict__ vT, const float* __restrict__ b3,
    float* __restrict__ out)
{
    __shared__ __align__(16) unsigned char smem[32768];
    __bf16* lds = (__bf16*)smem;     // buf b: e2t at elem b*8192, vTt at b*8192+4096
    float* scratch = (float*)smem;   // epilogue reuse

    const int t   = threadIdx.x;
    const int bid = blockIdx.x;
    const int x8 = bid & 7, jj = bid >> 3;
    const int bc = x8 * 4 + (jj >> 5), nt = jj & 31;

    const int w = t >> 6, l = t & 63;
    const int wn = w & 1, wm = w >> 1;
    const int l31 = l & 31, hi5 = l >> 5, l7 = l & 7, l3 = l >> 3;
    const int nbase = nt * 64 + wn * 32;

    const float bv0 = b3[l31], bv1 = b3[32 + l31];   // issue before first vmcnt

    bf16x8 e1f[4];
    {
        const __bf16* p = e1 + ((size_t)bc * NN + nbase + l31) * DD;
        #pragma unroll
        for (int kk = 0; kk < 4; ++kk)
            e1f[kk] = *(const bf16x8*)(p + kk * 16 + hi5 * 8);
    }

    f32x16 fz;
    #pragma unroll
    for (int i = 0; i < 16; ++i) fz[i] = 0.f;
    f32x16 hacc[2];
    #pragma unroll
    for (int fb = 0; fb < 2; ++fb)
        #pragma unroll
        for (int i = 0; i < 16; ++i) hacc[fb][i] = 0.f;

    const __bf16* e2h = e2 + (size_t)bc * NN * DD;
    const __bf16* vTh = vT + (size_t)bc * DD * NN;

    auto stage = [&](int b, int kt) {
        #pragma unroll
        for (int ii = 0; ii < 2; ++ii) {
            const int ch  = w * 2 + ii;
            const int row = ch * 8 + l3;
            const int q   = l7 ^ l3;
            gload16(e2h + ((size_t)(kt * 64 + row)) * DD + q * 8, &lds[b * 8192 + ch * 512]);
            gload16(vTh + ((size_t)row) * NN + kt * 64 + q * 8, &lds[b * 8192 + 4096 + ch * 512]);
        }
    };
    auto computeS = [&](int b, f32x16& sT) {
        const int rowoff = b * 8192 + (wm * 32 + l31) * 64;
        bf16x8 ef0 = *(const bf16x8*)&lds[rowoff + ((hi5) ^ l7) * 8];
        sT = mfma32(ef0, e1f[0], fz);
        #pragma unroll
        for (int kk = 1; kk < 4; ++kk) {
            bf16x8 ef = *(const bf16x8*)&lds[rowoff + ((kk * 2 + hi5) ^ l7) * 8];
            sT = mfma32(ef, e1f[kk], sT);
        }
    };
    auto loadVF = [&](int b, bf16x8 (&vf)[4]) {
        #pragma unroll
        for (int kk2 = 0; kk2 < 2; ++kk2) {
            const int slot = ((wm * 4 + kk2 * 2 + hi5) ^ l7) * 8;
            vf[kk2 * 2 + 0] = *(const bf16x8*)&lds[b * 8192 + 4096 + (l31) * 64 + slot];
            vf[kk2 * 2 + 1] = *(const bf16x8*)&lds[b * 8192 + 4096 + (32 + l31) * 64 + slot];
        }
    };
    auto packQ = [&](const f32x16& sT, i32x2 (&Q)[4]) {
        #pragma unroll
        for (int g = 0; g < 4; ++g) {
            bf16x4 q0;
            #pragma unroll
            for (int r = 0; r < 4; ++r) {
                float v = sT[4 * g + r];
                q0[r] = (__bf16)(v > 0.f ? v : 0.f);
            }
            Q[g] = __builtin_bit_cast(i32x2, q0);
        }
    };
    auto doPV = [&](i32x2 (&Q)[4], bf16x8 (&vf)[4]) {
        #pragma unroll
        for (int kk2 = 0; kk2 < 2; ++kk2) {
            int a0 = Q[2 * kk2][0],     a1 = Q[2 * kk2][1];
            int b0 = Q[2 * kk2 + 1][0], b1 = Q[2 * kk2 + 1][1];
            plswap(a0, b0);
            plswap(a1, b1);
            i32x4 pfi = { a0, a1, b0, b1 };
            bf16x8 pf = __builtin_bit_cast(bf16x8, pfi);
            hacc[0] = mfma32(pf, vf[kk2 * 2 + 0], hacc[0]);
            hacc[1] = mfma32(pf, vf[kk2 * 2 + 1], hacc[1]);
        }
    };

    i32x2 Qa[4], Qb[4];
    bf16x8 vfA[4], vfB[4];
    f32x16 sT;

    // prologue: tiles 0,1 staged; tile0 computed into regs
    stage(0, 0);
    stage(1, 1);
    asm volatile("s_waitcnt vmcnt(4)" ::: "memory");
    __builtin_amdgcn_sched_barrier(0);
    __builtin_amdgcn_s_barrier();
    computeS(0, sT);
    loadVF(0, vfA);
    packQ(sT, Qa);
    __builtin_amdgcn_s_barrier();

    for (int kt = 0; kt < 30; kt += 2) {
        // even half: stage tile kt+2 (buf0), compute S(kt+1) from buf1, PV(kt)
        stage(0, kt + 2);
        asm volatile("s_waitcnt vmcnt(4)" ::: "memory");
        __builtin_amdgcn_sched_barrier(0);
        __builtin_amdgcn_s_barrier();
        __builtin_amdgcn_s_setprio(1);
        computeS(1, sT);
        loadVF(1, vfB);
        doPV(Qa, vfA);
        __builtin_amdgcn_s_setprio(0);
        packQ(sT, Qb);
        __builtin_amdgcn_s_barrier();

        // odd half: stage tile kt+3 (buf1), compute S(kt+2) from buf0, PV(kt+1)
        stage(1, kt + 3);
        asm volatile("s_waitcnt vmcnt(4)" ::: "memory");
        __builtin_amdgcn_sched_barrier(0);
        __builtin_amdgcn_s_barrier();
        __builtin_amdgcn_s_setprio(1);
        computeS(0, sT);
        loadVF(0, vfA);
        doPV(Qb, vfB);
        __builtin_amdgcn_s_setprio(0);
        packQ(sT, Qa);
        __builtin_amdgcn_s_barrier();
    }

    // peel: tile31 (in buf1, 4 loads outstanding); PV(30) then PV(31)
    asm volatile("s_waitcnt vmcnt(0)" ::: "memory");
    __builtin_amdgcn_sched_barrier(0);
    __builtin_amdgcn_s_barrier();
    computeS(1, sT);
    loadVF(1, vfB);
    doPV(Qa, vfA);          // tile 30
    packQ(sT, Qb);
    doPV(Qb, vfB);          // tile 31

    // ---- epilogue: combine m-halves via LDS, add b3, store fp32 ----
    __syncthreads();
    if (wm == 1) {
        #pragma unroll
        for (int q = 0; q < 8; ++q) {
            f32x4 v;
            #pragma unroll
            for (int r = 0; r < 4; ++r) {
                const int idx = q * 4 + r;
                v[r] = hacc[idx >> 4][idx & 15];
            }
            *(f32x4*)&scratch[wn * 2048 + q * 256 + l * 4] = v;
        }
    }
    __syncthreads();
    if (wm == 0) {
        #pragma unroll
        for (int q = 0; q < 8; ++q) {
            f32x4 v = *(const f32x4*)&scratch[wn * 2048 + q * 256 + l * 4];
            #pragma unroll
            for (int r = 0; r < 4; ++r) {
                const int idx = q * 4 + r;
                hacc[idx >> 4][idx & 15] += v[r];
            }
        }
        const size_t ob = ((size_t)bc * NN + nbase) * DD;
        #pragma unroll
        for (int reg = 0; reg < 16; ++reg) {
            const int n = (reg & 3) + 8 * (reg >> 2) + 4 * hi5;
            out[ob + (size_t)n * DD + l31]      = hacc[0][reg] + bv0;
            out[ob + (size_t)n * DD + 32 + l31] = hacc[1][reg] + bv1;
        }
    }
}

extern "C" void kernel_launch(void* const* d_in, const int* in_sizes, int n_in,
                              void* d_out, int out_size, void* d_ws, size_t ws_size,
                              hipStream_t stream) {
    const float* x  = (const float*)d_in[0];
    const float* W1 = (const float*)d_in[1];
    const float* b1 = (const float*)d_in[2];
    const float* W2 = (const float*)d_in[3];
    const float* b2 = (const float*)d_in[4];
    const float* W3 = (const float*)d_in[5];
    const float* b3 = (const float*)d_in[6];
    float* out = (float*)d_out;

    __bf16* e1 = (__bf16*)d_ws;                       // 8 MB
    __bf16* e2 = e1 + (size_t)BCH * NN * DD;          // 8 MB
    __bf16* vT = e2 + (size_t)BCH * NN * DD;          // 8 MB

    prep_kernel<<<dim3(1024), dim3(256), 0, stream>>>(x, W1, b1, W2, b2, W3, e1, e2, vT);
    fused_kernel<<<dim3(1024), dim3(256), 0, stream>>>(e1, e2, vT, b3, out);
}

// Round 13
// 67.123 us; speedup vs baseline: 1.1396x; 1.1396x over previous
//
#include <hip/hip_runtime.h>
#include <hip/hip_bf16.h>

#define BCH 32   // B*C heads
#define NN  2048
#define DD  64   // F = H = O

typedef __attribute__((ext_vector_type(8)))  __bf16 bf16x8;
typedef __attribute__((ext_vector_type(4)))  __bf16 bf16x4;
typedef __attribute__((ext_vector_type(4)))  float  f32x4;
typedef __attribute__((ext_vector_type(16))) float  f32x16;
typedef __attribute__((ext_vector_type(2)))  int    i32x2;
typedef __attribute__((ext_vector_type(4)))  int    i32x4;
typedef __attribute__((ext_vector_type(2)))  unsigned int u32x2;

__device__ inline f32x4 mfma16(bf16x8 a, bf16x8 b, f32x4 c) {
    return __builtin_amdgcn_mfma_f32_16x16x32_bf16(a, b, c, 0, 0, 0);
}
__device__ inline f32x16 mfma32(bf16x8 a, bf16x8 b, f32x16 c) {
    return __builtin_amdgcn_mfma_f32_32x32x16_bf16(a, b, c, 0, 0, 0);
}
// permlane32_swap BUILTIN (validated round 9)
__device__ inline void plswap(int& a, int& b) {
    u32x2 r = __builtin_amdgcn_permlane32_swap((unsigned)a, (unsigned)b, false, false);
    a = (int)r[0];
    b = (int)r[1];
}

// ---------------------------------------------------------------------------
// Kernel 1 (v1 structure, validated rounds 6-11; e2/vT stores now go to
// FRAGMENT-LINEAR layouts for direct coalesced fragment loads in fused):
//   e1  [bc][n][h] row-major (unchanged)
//   E2F [bc][kt][c][r]: 16B chunk = e2[m=kt*64+r][h=c*8..c*8+8]  (4096 el/kt)
//   VTF [bc][kt][d][o]: 16B chunk = v^T[o][m=kt*64+d*8..+8]
// grid 1024 (32 bc x 32 strips), block 256 = 4 waves; wave w owns h-block w.
// ---------------------------------------------------------------------------
__global__ __launch_bounds__(256) void prep_kernel(
    const float* __restrict__ x,
    const float* __restrict__ W1, const float* __restrict__ b1,
    const float* __restrict__ W2, const float* __restrict__ b2,
    const float* __restrict__ W3,
    __bf16* __restrict__ e1, __bf16* __restrict__ e2f, __bf16* __restrict__ vtf)
{
    const int t   = threadIdx.x;
    const int blk = blockIdx.x;
    const int bc  = blk >> 5, st = blk & 31;
    const long grow = (long)bc * NN + st * 64;
    const int w = t >> 6, l = t & 63, lg = l >> 4, li = l & 15;

    bf16x8 a[4][2];
    #pragma unroll
    for (int nb = 0; nb < 4; ++nb)
        #pragma unroll
        for (int kk = 0; kk < 2; ++kk) {
            const float* p = x + (grow + nb * 16 + li) * DD + kk * 32 + lg * 8;
            f32x4 v0 = *(const f32x4*)p, v1 = *(const f32x4*)(p + 4);
            #pragma unroll
            for (int j = 0; j < 4; ++j) {
                a[nb][kk][j]     = (__bf16)v0[j];
                a[nb][kk][4 + j] = (__bf16)v1[j];
            }
        }

    bf16x8 wf1[2], wf2[2], wf3[2];
    #pragma unroll
    for (int kk = 0; kk < 2; ++kk) {
        const float* p1 = W1 + (w * 16 + li) * DD + kk * 32 + lg * 8;
        const float* p2 = W2 + (w * 16 + li) * DD + kk * 32 + lg * 8;
        const float* p3 = W3 + (w * 16 + li) * DD + kk * 32 + lg * 8;
        f32x4 u0 = *(const f32x4*)p1, u1 = *(const f32x4*)(p1 + 4);
        f32x4 v0 = *(const f32x4*)p2, v1 = *(const f32x4*)(p2 + 4);
        f32x4 t0 = *(const f32x4*)p3, t1 = *(const f32x4*)(p3 + 4);
        #pragma unroll
        for (int j = 0; j < 4; ++j) {
            wf1[kk][j] = (__bf16)u0[j]; wf1[kk][4 + j] = (__bf16)u1[j];
            wf2[kk][j] = (__bf16)v0[j]; wf2[kk][4 + j] = (__bf16)v1[j];
            wf3[kk][j] = (__bf16)t0[j]; wf3[kk][4 + j] = (__bf16)t1[j];
        }
    }
    const f32x4 bq1 = *(const f32x4*)(b1 + w * 16 + lg * 4);
    const f32x4 bq2 = *(const f32x4*)(b2 + w * 16 + lg * 4);

    const size_t ktbase = (size_t)(bc * 32 + st) * 4096;   // elems per kt block

    #pragma unroll
    for (int nb = 0; nb < 4; ++nb) {
        f32x4 acc1 = {0.f,0.f,0.f,0.f}, acc2 = {0.f,0.f,0.f,0.f}, acc3 = {0.f,0.f,0.f,0.f};
        #pragma unroll
        for (int kk = 0; kk < 2; ++kk) {
            acc1 = mfma16(wf1[kk], a[nb][kk], acc1);   // D[h][n]
            acc2 = mfma16(wf2[kk], a[nb][kk], acc2);   // D[h][n]
            acc3 = mfma16(a[nb][kk], wf3[kk], acc3);   // D[n][o]
        }
        bf16x4 q1, q2, q3;
        #pragma unroll
        for (int r = 0; r < 4; ++r) {
            q1[r] = (__bf16)(acc1[r] + bq1[r]);
            q2[r] = (__bf16)(acc2[r] + bq2[r]);
            q3[r] = (__bf16)acc3[r];
        }
        // e1 row-major: n = grow + nb*16 + li, h-quad = w*16 + lg*4
        *(bf16x4*)&e1[(grow + nb * 16 + li) * DD + w * 16 + lg * 4] = q1;
        // E2F: c = w*2 + (lg>>1), r = nb*16 + li, half = lg&1
        *(bf16x4*)&e2f[ktbase + (w * 2 + (lg >> 1)) * 512 + (nb * 16 + li) * 8 + (lg & 1) * 4] = q2;
        // VTF: d = nb*2 + (lg>>1), o = w*16 + li, half = lg&1
        *(bf16x4*)&vtf[ktbase + (nb * 2 + (lg >> 1)) * 512 + (w * 16 + li) * 8 + (lg & 1) * 4] = q3;
    }
}

// ---------------------------------------------------------------------------
// Kernel 2 v4: NO LDS / NO BARRIERS in the K-loop. Fragments loaded directly
// from L2-resident fragment-linear buffers (coalesced 2x512B per instr).
// grid 1024 (XCD-grouped), block 256 = 4 waves (2 wn x 2 wm); waves fully
// independent; even/odd register prefetch of next tile.
// ---------------------------------------------------------------------------
__global__ __launch_bounds__(256, 3) void fused_kernel(
    const __bf16* __restrict__ e1, const __bf16* __restrict__ e2f,
    const __bf16* __restrict__ vtf, const float* __restrict__ b3,
    float* __restrict__ out)
{
    __shared__ float scratch[8192];      // epilogue m-half combine only (32KB)

    const int t   = threadIdx.x;
    const int bid = blockIdx.x;
    const int x8 = bid & 7, jj = bid >> 3;
    const int bc = x8 * 4 + (jj >> 5), nt = jj & 31;

    const int w = t >> 6, l = t & 63;
    const int wn = w & 1, wm = w >> 1;
    const int l31 = l & 31, hi5 = l >> 5;
    const int nbase = nt * 64 + wn * 32;

    const float bv0 = b3[l31], bv1 = b3[32 + l31];

    bf16x8 e1f[4];
    {
        const __bf16* p = e1 + ((size_t)bc * NN + nbase + l31) * DD;
        #pragma unroll
        for (int kk = 0; kk < 4; ++kk)
            e1f[kk] = *(const bf16x8*)(p + kk * 16 + hi5 * 8);
    }

    f32x16 fz;
    #pragma unroll
    for (int i = 0; i < 16; ++i) fz[i] = 0.f;
    f32x16 hacc[2];
    #pragma unroll
    for (int fb = 0; fb < 2; ++fb)
        #pragma unroll
        for (int i = 0; i < 16; ++i) hacc[fb][i] = 0.f;

    // per-lane fragment base pointers (constant lane offsets hoisted)
    const __bf16* E2 = e2f + (size_t)bc * 131072 + hi5 * 512 + (wm * 32 + l31) * 8;
    const __bf16* VT = vtf + (size_t)bc * 131072 + (wm * 4 + hi5) * 512 + l31 * 8;

    auto loadEF = [&](int kt, bf16x8 (&ef)[4]) {
        const __bf16* p = E2 + (size_t)kt * 4096;
        #pragma unroll
        for (int kk = 0; kk < 4; ++kk)
            ef[kk] = *(const bf16x8*)(p + kk * 1024);
    };
    auto loadVF = [&](int kt, bf16x8 (&vf)[4]) {
        const __bf16* p = VT + (size_t)kt * 4096;
        #pragma unroll
        for (int kk2 = 0; kk2 < 2; ++kk2) {
            vf[kk2 * 2 + 0] = *(const bf16x8*)(p + kk2 * 1024);
            vf[kk2 * 2 + 1] = *(const bf16x8*)(p + kk2 * 1024 + 256);
        }
    };
    auto computeS = [&](bf16x8 (&ef)[4], f32x16& sT) {
        sT = mfma32(ef[0], e1f[0], fz);
        #pragma unroll
        for (int kk = 1; kk < 4; ++kk)
            sT = mfma32(ef[kk], e1f[kk], sT);
    };
    auto packQ = [&](const f32x16& sT, i32x2 (&Q)[4]) {
        #pragma unroll
        for (int g = 0; g < 4; ++g) {
            bf16x4 q0;
            #pragma unroll
            for (int r = 0; r < 4; ++r) {
                float v = sT[4 * g + r];
                q0[r] = (__bf16)(v > 0.f ? v : 0.f);
            }
            Q[g] = __builtin_bit_cast(i32x2, q0);
        }
    };
    auto doPV = [&](i32x2 (&Q)[4], bf16x8 (&vf)[4]) {
        #pragma unroll
        for (int kk2 = 0; kk2 < 2; ++kk2) {
            int a0 = Q[2 * kk2][0],     a1 = Q[2 * kk2][1];
            int b0 = Q[2 * kk2 + 1][0], b1 = Q[2 * kk2 + 1][1];
            plswap(a0, b0);
            plswap(a1, b1);
            i32x4 pfi = { a0, a1, b0, b1 };
            bf16x8 pf = __builtin_bit_cast(bf16x8, pfi);
            hacc[0] = mfma32(pf, vf[kk2 * 2 + 0], hacc[0]);
            hacc[1] = mfma32(pf, vf[kk2 * 2 + 1], hacc[1]);
        }
    };

    bf16x8 efA[4], vfA[4], efB[4], vfB[4];
    i32x2 Qa[4], Qb[4];
    f32x16 sT;

    loadEF(0, efA); loadVF(0, vfA);
    for (int kt = 0; kt < 32; kt += 2) {
        loadEF(kt + 1, efB); loadVF(kt + 1, vfB);   // prefetch odd tile
        computeS(efA, sT);
        packQ(sT, Qa);
        doPV(Qa, vfA);
        if (kt + 2 < 32) { loadEF(kt + 2, efA); loadVF(kt + 2, vfA); }  // prefetch next even
        computeS(efB, sT);
        packQ(sT, Qb);
        doPV(Qb, vfB);
    }

    // ---- epilogue: combine m-halves via LDS, add b3, store fp32 ----
    if (wm == 1) {
        #pragma unroll
        for (int q = 0; q < 8; ++q) {
            f32x4 v;
            #pragma unroll
            for (int r = 0; r < 4; ++r) {
                const int idx = q * 4 + r;
                v[r] = hacc[idx >> 4][idx & 15];
            }
            *(f32x4*)&scratch[wn * 2048 + q * 256 + l * 4] = v;
        }
    }
    __syncthreads();
    if (wm == 0) {
        #pragma unroll
        for (int q = 0; q < 8; ++q) {
            f32x4 v = *(const f32x4*)&scratch[wn * 2048 + q * 256 + l * 4];
            #pragma unroll
            for (int r = 0; r < 4; ++r) {
                const int idx = q * 4 + r;
                hacc[idx >> 4][idx & 15] += v[r];
            }
        }
        const size_t ob = ((size_t)bc * NN + nbase) * DD;
        #pragma unroll
        for (int reg = 0; reg < 16; ++reg) {
            const int n = (reg & 3) + 8 * (reg >> 2) + 4 * hi5;
            out[ob + (size_t)n * DD + l31]      = hacc[0][reg] + bv0;
            out[ob + (size_t)n * DD + 32 + l31] = hacc[1][reg] + bv1;
        }
    }
}

extern "C" void kernel_launch(void* const* d_in, const int* in_sizes, int n_in,
                              void* d_out, int out_size, void* d_ws, size_t ws_size,
                              hipStream_t stream) {
    const float* x  = (const float*)d_in[0];
    const float* W1 = (const float*)d_in[1];
    const float* b1 = (const float*)d_in[2];
    const float* W2 = (const float*)d_in[3];
    const float* b2 = (const float*)d_in[4];
    const float* W3 = (const float*)d_in[5];
    const float* b3 = (const float*)d_in[6];
    float* out = (float*)d_out;

    __bf16* e1  = (__bf16*)d_ws;                      // 8 MB
    __bf16* e2f = e1 + (size_t)BCH * NN * DD;         // 8 MB fragment-linear
    __bf16* vtf = e2f + (size_t)BCH * NN * DD;        // 8 MB fragment-linear

    prep_kernel<<<dim3(1024), dim3(256), 0, stream>>>(x, W1, b1, W2, b2, W3, e1, e2f, vtf);
    fused_kernel<<<dim3(1024), dim3(256), 0, stream>>>(e1, e2f, vtf, b3, out);
}